// Round 5
// baseline (78.748 us; speedup 1.0000x reference)
//
#include <hip/hip_runtime.h>
#include <hip/hip_bf16.h>

// Problem constants
#define L_SEQ   4096
#define D_IN    1024
#define N_BATCH 16
#define L_OUT   1024
#define D_OUT   1024
#define M_DIM   (N_BATCH * L_OUT)   // 16384
#define K_DIM   D_IN

// GEMM tiling (256x256 8-phase template)
#define BM 256
#define BN 256
#define BK 64
#define NKT (K_DIM / BK)   // 16

typedef __attribute__((ext_vector_type(4))) float  f32x4;
typedef __attribute__((ext_vector_type(8))) __bf16 bf16x8;
typedef __attribute__((ext_vector_type(4))) __bf16 bf16x4;

// ws layout (bytes): W bf16 (2 MiB) + s_arr
#define WS_W_OFF 0u
#define WS_S_OFF (4u * 1024u * 1024u)

// ---------------------------------------------------------------------------
// Kernel 1 (merged prep): blocks 0..15 -> mask sums; blocks 16..1039 -> W rows
// W rows written bf16, pre-swizzled: elem e -> (e&~63) | ((e&63) ^ ((row&7)<<3))
// ---------------------------------------------------------------------------
__global__ __launch_bounds__(256) void prep_kernel(
    const int*   __restrict__ mask,  // (16, 4096)
    const float* __restrict__ W,     // (1024, 1024)
    int*    __restrict__ s_out,      // (16,)
    __bf16* __restrict__ wsW)        // (1024, 1024) swizzled
{
    const int t = threadIdx.x;
    if (blockIdx.x < 16) {
        const int b = blockIdx.x;
        const int* row = mask + (size_t)b * L_SEQ;
        int sum = 0;
#pragma unroll
        for (int i = 0; i < L_SEQ / 256; ++i) sum += row[t + i * 256];
#pragma unroll
        for (int off = 32; off > 0; off >>= 1) sum += __shfl_down(sum, off, 64);
        __shared__ int wsum[4];
        if ((t & 63) == 0) wsum[t >> 6] = sum;
        __syncthreads();
        if (t == 0) {
            int total = wsum[0] + wsum[1] + wsum[2] + wsum[3];
            s_out[b] = total < L_OUT ? total : L_OUT;
        }
    } else {
        const int n  = blockIdx.x - 16;          // 0..1023
        const int e0 = t * 4;
        const int rsw  = (n & 7) << 3;
        const int dste = (e0 & ~63) | ((e0 & 63) ^ rsw);
        const float* src = W + (size_t)n * D_IN + e0;
        f32x4 v = *(const f32x4*)src;
        bf16x4 o = {(__bf16)v.x, (__bf16)v.y, (__bf16)v.z, (__bf16)v.w};
        *(bf16x4*)(wsW + (size_t)n * K_DIM + dste) = o;
    }
}

// ---------------------------------------------------------------------------
// Kernel 2: fused restrict+cast+GEMM.  out[m,n] = sum_k A[m,k]*W[n,k] + b[n]
//   A[m,k] = (j < s_b) ? bf16(x[b, L-s_b+j, k]) : 0,  b=m>>10, j=m&1023.
// 256x256 8-phase, 8 waves (2Mx4N), double-buffered LDS (128 KiB).
// B: ws-pre-swizzled bf16, linear-dest global_load_lds.
// A: reg-staged from fp32 x (T14): issue 8xdwordx4 at P4(kt-1), cvt+swizzled
//    ds_write split across P3/P4(kt) into buf nxt.
// vmcnt ledger (verified): per-iter issue order [2 B-lds(P2), 2 B-lds(P4),
// 8 A-glb(P4)] -> P1 vmcnt(8) retires exactly the 4 B-lds of cur; cvt's reg
// waits are compiler-auto (in-order retirement leaves later B-lds flying).
// ---------------------------------------------------------------------------
__device__ __forceinline__ void gload16(const __bf16* g, __bf16* l) {
    __builtin_amdgcn_global_load_lds(
        (const __attribute__((address_space(1))) void*)g,
        (__attribute__((address_space(3))) void*)l,
        16, 0, 0);
}

#define FENCE() asm volatile("" ::: "memory")

__global__ __launch_bounds__(512, 2) void gemm_kernel(
    const float*  __restrict__ x,    // (16, 4096, 1024) fp32
    const __bf16* __restrict__ Wb,   // (1024, 1024) swizzled bf16
    const float*  __restrict__ bias, // (1024,)
    const int*    __restrict__ s_arr,// (16,)
    float* __restrict__ out)         // (16384, 1024)
{
    __shared__ __bf16 sA[2][BM * BK];   // 64 KiB
    __shared__ __bf16 sB[2][BN * BK];   // 64 KiB

    const int t  = threadIdx.x;       // 0..511
    const int bx = blockIdx.x;        // 256 blocks
    const int tile_n = bx & 3;        // N/BN = 4
    const int tile_m = bx >> 2;       // M/BM = 64
    const int m0 = tile_m * BM;
    const int n0 = tile_n * BN;
    const int lane = t & 63;
    const int wave = t >> 6;
    const int wm = wave >> 2;         // 0..1
    const int wn = wave & 3;          // 0..3

    // ---- B staging (gload_lds, linear): 64 rows x 64 cols per round ----
    const int srow = t >> 3;          // 0..63
    const int scol = (t & 7) * 8;     // elem col (linear; ws content swizzled)
    const __bf16* Bg = Wb + (size_t)n0 * K_DIM;

#define STAGE_B_HALF(dstB, h, kt_)                                         \
    {                                                                      \
        _Pragma("unroll")                                                  \
        for (int rd = 0; rd < 2; ++rd) {                                   \
            const int r_ = (h) * 128 + rd * 64 + srow;                     \
            gload16(Bg + (size_t)r_ * K_DIM + (kt_) * BK + scol,           \
                    (dstB) + r_ * BK + scol);                              \
        }                                                                  \
    }

    // ---- A staging (reg-staged fp32 -> cvt -> swizzled ds_write) ----
    // thread covers rows ar+32*l (l=0..7), fp32 cols [ac, ac+4)
    const int ar = t >> 4;            // 0..31
    const int ac = (t & 15) * 4;      // 0..60
    const int bb = tile_m >> 2;       // batch (4 M-tiles per batch)
    const int s  = s_arr[bb];
    const int jbase = (tile_m & 3) * 256;
    const float* xb = x + (size_t)bb * L_SEQ * D_IN + (size_t)(L_SEQ - s) * D_IN;

    int aoff[8];
#pragma unroll
    for (int l = 0; l < 8; ++l) {
        const int j  = jbase + ar + 32 * l;
        const int jc = (j < s) ? j : 0;          // clamped-safe address
        aoff[l] = jc * D_IN + ac;
    }

    f32x4 areg[8];
    const f32x4 zf = {0.f, 0.f, 0.f, 0.f};

#define ISSUE_A(kt_)                                                       \
    {                                                                      \
        _Pragma("unroll")                                                  \
        for (int l = 0; l < 8; ++l)                                        \
            areg[l] = *(const f32x4*)(xb + aoff[l] + (kt_) * BK);          \
    }

    // zero-select deferred to cvt time so no vmcnt wait is forced at issue
#define CVT_A(dstA, l0_)                                                   \
    {                                                                      \
        _Pragma("unroll")                                                  \
        for (int l = (l0_); l < (l0_) + 4; ++l) {                          \
            const int j_   = jbase + ar + 32 * l;                          \
            const int row_ = ar + 32 * l;                                  \
            f32x4 v = (j_ < s) ? areg[l] : zf;                             \
            bf16x4 o = {(__bf16)v.x, (__bf16)v.y, (__bf16)v.z, (__bf16)v.w}; \
            *(bf16x4*)&(dstA)[row_ * BK + (ac ^ ((row_ & 7) << 3))] = o;   \
        }                                                                  \
    }

    // ---- fragment read geometry (XOR-swizzled ds_read_b128) ----
    const int fr  = lane & 15;
    const int k8  = (lane >> 4) * 8;
    const int swz = (fr & 7) << 3;
    const int kc0 = k8 ^ swz;
    const int kc1 = (32 + k8) ^ swz;

    bf16x8 aF[4][2], bF0[2][2], bF1[2][2];
    f32x4 acc[8][4];
#pragma unroll
    for (int f = 0; f < 8; ++f)
#pragma unroll
        for (int g = 0; g < 4; ++g) acc[f][g] = (f32x4){0.f, 0.f, 0.f, 0.f};

#define LOAD_AF(Ac, mh)                                                    \
    {                                                                      \
        const __bf16* rb_ = (Ac) + (wm * 128 + (mh) * 64 + fr) * BK;       \
        _Pragma("unroll")                                                  \
        for (int i = 0; i < 4; ++i) {                                      \
            aF[i][0] = *(const bf16x8*)&rb_[i * 16 * BK + kc0];            \
            aF[i][1] = *(const bf16x8*)&rb_[i * 16 * BK + kc1];            \
        }                                                                  \
    }

#define LOAD_BF(Bc, nh, bF)                                                \
    {                                                                      \
        const __bf16* rb_ = (Bc) + (wn * 64 + (nh) * 32 + fr) * BK;        \
        _Pragma("unroll")                                                  \
        for (int j = 0; j < 2; ++j) {                                      \
            bF[j][0] = *(const bf16x8*)&rb_[j * 16 * BK + kc0];            \
            bF[j][1] = *(const bf16x8*)&rb_[j * 16 * BK + kc1];            \
        }                                                                  \
    }

#define MFMA_QUAD(mh, nh, bF)                                              \
    {                                                                      \
        _Pragma("unroll")                                                  \
        for (int i = 0; i < 4; ++i)                                        \
            _Pragma("unroll")                                              \
            for (int j = 0; j < 2; ++j) {                                  \
                f32x4 c_ = acc[(mh) * 4 + i][(nh) * 2 + j];                \
                c_ = __builtin_amdgcn_mfma_f32_16x16x32_bf16(              \
                    aF[i][0], bF[j][0], c_, 0, 0, 0);                      \
                c_ = __builtin_amdgcn_mfma_f32_16x16x32_bf16(              \
                    aF[i][1], bF[j][1], c_, 0, 0, 0);                      \
                acc[(mh) * 4 + i][(nh) * 2 + j] = c_;                      \
            }                                                              \
    }

    // ---- prologue ----
    // issue order fixes the ledger: [8 A-glb(0)][4 B-lds(0)] -> cvt A(0)
    // (auto-wait retires A(0), B flies) -> [8 A-glb(1)] -> 12 outstanding.
    ISSUE_A(0);
    STAGE_B_HALF(sB[0], 0, 0);
    STAGE_B_HALF(sB[0], 1, 0);
    CVT_A(sA[0], 0);
    CVT_A(sA[0], 4);
    ISSUE_A(1);
    asm volatile("s_waitcnt lgkmcnt(0)" ::: "memory");
    __builtin_amdgcn_sched_barrier(0);

    for (int kt = 0; kt < NKT; ++kt) {
        const int cur = kt & 1;
        __bf16* Ac = sA[cur];
        __bf16* Bc = sB[cur];
        __bf16* An = sA[cur ^ 1];
        __bf16* Bn = sB[cur ^ 1];

        // ---- P1: quadrant (0,0) ----
        FENCE();
        if (kt == NKT - 1) asm volatile("s_waitcnt vmcnt(0)" ::: "memory");
        else               asm volatile("s_waitcnt vmcnt(8)" ::: "memory");
        __builtin_amdgcn_s_barrier();
        FENCE();
        LOAD_AF(Ac, 0);
        LOAD_BF(Bc, 0, bF0);
        asm volatile("s_waitcnt lgkmcnt(0)" ::: "memory");
        __builtin_amdgcn_sched_barrier(0);
        __builtin_amdgcn_s_setprio(1);
        MFMA_QUAD(0, 0, bF0);
        __builtin_amdgcn_s_setprio(0);

        // ---- P2: quadrant (0,1) ----
        FENCE();
        __builtin_amdgcn_s_barrier();
        FENCE();
        if (kt + 1 < NKT) STAGE_B_HALF(Bn, 0, kt + 1);
        LOAD_BF(Bc, 1, bF1);
        asm volatile("s_waitcnt lgkmcnt(0)" ::: "memory");
        __builtin_amdgcn_sched_barrier(0);
        __builtin_amdgcn_s_setprio(1);
        MFMA_QUAD(0, 1, bF1);
        __builtin_amdgcn_s_setprio(0);

        // ---- P3: quadrant (1,1) ----
        FENCE();
        __builtin_amdgcn_s_barrier();
        FENCE();
        LOAD_AF(Ac, 1);
        if (kt + 1 < NKT) CVT_A(An, 0);   // auto vmcnt wait for areg l0-3
        asm volatile("s_waitcnt lgkmcnt(0)" ::: "memory");
        __builtin_amdgcn_sched_barrier(0);
        __builtin_amdgcn_s_setprio(1);
        MFMA_QUAD(1, 1, bF1);
        __builtin_amdgcn_s_setprio(0);

        // ---- P4: quadrant (1,0) ----
        FENCE();
        __builtin_amdgcn_s_barrier();
        FENCE();
        if (kt + 1 < NKT) {
            STAGE_B_HALF(Bn, 1, kt + 1);
            CVT_A(An, 4);                 // auto vmcnt wait for areg l4-7
        }
        if (kt + 2 < NKT) ISSUE_A(kt + 2);
        __builtin_amdgcn_s_setprio(1);
        MFMA_QUAD(1, 0, bF0);
        __builtin_amdgcn_s_setprio(0);
        // drain this iteration's ds_writes before next P1 barrier
        asm volatile("s_waitcnt lgkmcnt(0)" ::: "memory");
        __builtin_amdgcn_sched_barrier(0);
    }

    // ---- epilogue: bias + store ----
    float bias_v[4];
#pragma unroll
    for (int g = 0; g < 4; ++g)
        bias_v[g] = bias[n0 + wn * 64 + g * 16 + fr];

    const int row0 = m0 + wm * 128 + (lane >> 4) * 4;
    const int col0 = n0 + wn * 64 + fr;
#pragma unroll
    for (int f = 0; f < 8; ++f)
#pragma unroll
        for (int g = 0; g < 4; ++g)
#pragma unroll
            for (int rr = 0; rr < 4; ++rr)
                out[(size_t)(row0 + f * 16 + rr) * D_OUT + (col0 + g * 16)] =
                    acc[f][g][rr] + bias_v[g];

#undef STAGE_B_HALF
#undef ISSUE_A
#undef CVT_A
#undef LOAD_AF
#undef LOAD_BF
#undef MFMA_QUAD
}

// ---------------------------------------------------------------------------
extern "C" void kernel_launch(void* const* d_in, const int* in_sizes, int n_in,
                              void* d_out, int out_size, void* d_ws, size_t ws_size,
                              hipStream_t stream) {
    const float* x    = (const float*)d_in[0];
    const int*   mask = (const int*)d_in[1];
    const float* W    = (const float*)d_in[2];
    const float* bias = (const float*)d_in[3];
    float*       out  = (float*)d_out;

    __bf16* wsW   = (__bf16*)((char*)d_ws + WS_W_OFF);
    int*    s_arr = (int*)((char*)d_ws + WS_S_OFF);

    prep_kernel<<<dim3(16 + D_OUT), dim3(256), 0, stream>>>(
        mask, W, s_arr, wsW);

    const int grid = (M_DIM / BM) * (D_OUT / BN);  // 64 * 4 = 256
    gemm_kernel<<<dim3(grid), dim3(512), 0, stream>>>(
        x, wsW, bias, s_arr, out);
}

// Round 6
// 62.050 us; speedup vs baseline: 1.2691x; 1.2691x over previous
//
#include <hip/hip_runtime.h>
#include <hip/hip_bf16.h>

// Problem constants
#define L_SEQ   4096
#define D_IN    1024
#define N_BATCH 16
#define L_OUT   1024
#define D_OUT   1024
#define M_DIM   (N_BATCH * L_OUT)   // 16384
#define K_DIM   D_IN

// GEMM tiling (256x256 8-phase template)
#define BM 256
#define BN 256
#define BK 64
#define NKT (K_DIM / BK)   // 16

typedef __attribute__((ext_vector_type(4))) float  f32x4;
typedef __attribute__((ext_vector_type(8))) __bf16 bf16x8;
typedef __attribute__((ext_vector_type(4))) __bf16 bf16x4;

// ws layout (bytes)
#define WS_A_OFF 0u
#define WS_W_OFF (32u * 1024u * 1024u)
#define WS_S_OFF (WS_W_OFF + 2u * 1024u * 1024u)

// ---------------------------------------------------------------------------
// Kernel 1: s[b] = min(sum(attention_mask[b,:]), L_OUT)
// ---------------------------------------------------------------------------
__global__ __launch_bounds__(256) void mask_sum_kernel(
    const int* __restrict__ mask, int* __restrict__ s_out)
{
    const int b = blockIdx.x;
    const int t = threadIdx.x;
    const int* row = mask + (size_t)b * L_SEQ;

    int sum = 0;
#pragma unroll
    for (int i = 0; i < L_SEQ / 256; ++i) sum += row[t + i * 256];

#pragma unroll
    for (int off = 32; off > 0; off >>= 1) sum += __shfl_down(sum, off, 64);

    __shared__ int wsum[4];
    if ((t & 63) == 0) wsum[t >> 6] = sum;
    __syncthreads();
    if (t == 0) {
        int total = wsum[0] + wsum[1] + wsum[2] + wsum[3];
        s_out[b] = total < L_OUT ? total : L_OUT;
    }
}

// ---------------------------------------------------------------------------
// Kernel 2: build bf16 A (restricted+zero-padded) and bf16 W in ws,
// pre-swizzled per row: elem e -> (e & ~63) | ((e & 63) ^ ((row&7)<<3)).
// GEMM stages with LINEAR source columns (content already permuted) and
// linear-dest global_load_lds; the ds_read side applies the same XOR.
// ---------------------------------------------------------------------------
__global__ __launch_bounds__(256) void convert_kernel(
    const float* __restrict__ x,     // (16, 4096, 1024)
    const float* __restrict__ W,     // (1024, 1024)
    const int*   __restrict__ s_arr, // (16,)
    __bf16* __restrict__ wsA,        // (16384, 1024)
    __bf16* __restrict__ wsW)        // (1024, 1024)
{
    const int rid = blockIdx.x;
    const int t   = threadIdx.x;
    const int e0  = t * 4;

    if (rid < M_DIM) {
        const int b = rid >> 10;
        const int j = rid & (L_OUT - 1);
        const int s = s_arr[b];
        const int rsw  = (rid & 7) << 3;
        const int dste = (e0 & ~63) | ((e0 & 63) ^ rsw);
        __bf16* dst = wsA + (size_t)rid * K_DIM + dste;
        if (j < s) {
            const float* src = x + ((size_t)b * L_SEQ + (L_SEQ - s + j)) * D_IN + e0;
            f32x4 v = *(const f32x4*)src;
            bf16x4 o = {(__bf16)v.x, (__bf16)v.y, (__bf16)v.z, (__bf16)v.w};
            *(bf16x4*)dst = o;
        } else {
            bf16x4 o = {(__bf16)0.f, (__bf16)0.f, (__bf16)0.f, (__bf16)0.f};
            *(bf16x4*)dst = o;
        }
    } else {
        const int n = rid - M_DIM;
        const int rsw  = (n & 7) << 3;
        const int dste = (e0 & ~63) | ((e0 & 63) ^ rsw);
        const float* src = W + (size_t)n * D_IN + e0;
        f32x4 v = *(const f32x4*)src;
        bf16x4 o = {(__bf16)v.x, (__bf16)v.y, (__bf16)v.z, (__bf16)v.w};
        *(bf16x4*)(wsW + (size_t)n * K_DIM + dste) = o;
    }
}

// ---------------------------------------------------------------------------
// Kernel 3: 256x256 8-phase GEMM.  out[m,n] = sum_k A[m,k]*W[n,k] + bias[n]
// 8 waves (2M x 4N), per-wave out 128x64, acc[8][4] f32x4.
// Double-buffered LDS (128 KiB), half-tile (128x64) stage granularity,
// counted vmcnt (never 0 in steady state), setprio around MFMA clusters.
// Per-thread load ledger (verified): buf(kt) = {kt-2:P3,P4 ; kt-1:P1};
// at kt's P1 the 4 newest outstanding are kt-1:P3,P4 -> vmcnt(4) is exact.
// T1 XCD swizzle: vb=(bx&7)*32+(bx>>3) (bijective) groups the 4 tile_n
// sharers of each tile_m onto ONE XCD -> per-XCD A working set = 4MB = L2.
// ---------------------------------------------------------------------------
__device__ __forceinline__ void gload16(const __bf16* g, __bf16* l) {
    __builtin_amdgcn_global_load_lds(
        (const __attribute__((address_space(1))) void*)g,
        (__attribute__((address_space(3))) void*)l,
        16, 0, 0);
}

#define FENCE() asm volatile("" ::: "memory")

__global__ __launch_bounds__(512, 2) void gemm_kernel(
    const __bf16* __restrict__ A,    // (16384, 1024) swizzled rows
    const __bf16* __restrict__ Wb,   // (1024, 1024)  swizzled rows
    const float*  __restrict__ bias, // (1024,)
    float* __restrict__ out)         // (16384, 1024)
{
    __shared__ __bf16 smem[2][2][BM * BK];   // 128 KiB

    const int t  = threadIdx.x;       // 0..511
    const int bx = blockIdx.x;        // 256 blocks
    const int vb = (bx & 7) * 32 + (bx >> 3);  // XCD-grouping swizzle
    const int tile_n = vb & 3;        // N/BN = 4
    const int tile_m = vb >> 2;       // M/BM = 64
    const int m0 = tile_m * BM;
    const int n0 = tile_n * BN;
    const int lane = t & 63;
    const int wave = t >> 6;
    const int wm = wave >> 2;         // 0..1
    const int wn = wave & 3;          // 0..3

    // staging geometry: per gload round, 64 rows x 64 cols; LINEAR src cols
    // (ws content is already swizzled; LDS inherits the swizzled layout).
    const int srow = t >> 3;          // 0..63
    const int scol = (t & 7) * 8;     // linear source elem col
    const int sdst = (t & 7) * 8;     // linear LDS elem col

    const __bf16* Ag = A  + (size_t)m0 * K_DIM;
    const __bf16* Bg = Wb + (size_t)n0 * K_DIM;

#define STAGE_HALF(gbase, lbase, h, kt_)                                   \
    {                                                                      \
        _Pragma("unroll")                                                  \
        for (int rd = 0; rd < 2; ++rd) {                                   \
            const int r_ = (h) * 128 + rd * 64 + srow;                     \
            gload16((gbase) + (size_t)r_ * K_DIM + (kt_) * BK + scol,      \
                    (lbase) + r_ * BK + sdst);                             \
        }                                                                  \
    }

    // fragment read geometry
    const int fr  = lane & 15;
    const int k8  = (lane >> 4) * 8;
    const int swz = (fr & 7) << 3;
    const int kc0 = k8 ^ swz;
    const int kc1 = (32 + k8) ^ swz;

    // bias hoisted ahead of the K-loop (latency hidden under prologue)
    float bias_v[4];
#pragma unroll
    for (int g = 0; g < 4; ++g)
        bias_v[g] = bias[n0 + wn * 64 + g * 16 + fr];

    bf16x8 aF[4][2], bF0[2][2], bF1[2][2];
    f32x4 acc[8][4];
#pragma unroll
    for (int f = 0; f < 8; ++f)
#pragma unroll
        for (int g = 0; g < 4; ++g) acc[f][g] = (f32x4){0.f, 0.f, 0.f, 0.f};

#define LOAD_AF(Ac, mh)                                                    \
    {                                                                      \
        const __bf16* rb_ = (Ac) + (wm * 128 + (mh) * 64 + fr) * BK;       \
        _Pragma("unroll")                                                  \
        for (int i = 0; i < 4; ++i) {                                      \
            aF[i][0] = *(const bf16x8*)&rb_[i * 16 * BK + kc0];            \
            aF[i][1] = *(const bf16x8*)&rb_[i * 16 * BK + kc1];            \
        }                                                                  \
    }

#define LOAD_BF(Bc, nh, bF)                                                \
    {                                                                      \
        const __bf16* rb_ = (Bc) + (wn * 64 + (nh) * 32 + fr) * BK;        \
        _Pragma("unroll")                                                  \
        for (int j = 0; j < 2; ++j) {                                      \
            bF[j][0] = *(const bf16x8*)&rb_[j * 16 * BK + kc0];            \
            bF[j][1] = *(const bf16x8*)&rb_[j * 16 * BK + kc1];            \
        }                                                                  \
    }

#define MFMA_QUAD(mh, nh, bF)                                              \
    {                                                                      \
        _Pragma("unroll")                                                  \
        for (int i = 0; i < 4; ++i)                                        \
            _Pragma("unroll")                                              \
            for (int j = 0; j < 2; ++j) {                                  \
                f32x4 c_ = acc[(mh) * 4 + i][(nh) * 2 + j];                \
                c_ = __builtin_amdgcn_mfma_f32_16x16x32_bf16(              \
                    aF[i][0], bF[j][0], c_, 0, 0, 0);                      \
                c_ = __builtin_amdgcn_mfma_f32_16x16x32_bf16(              \
                    aF[i][1], bF[j][1], c_, 0, 0, 0);                      \
                acc[(mh) * 4 + i][(nh) * 2 + j] = c_;                      \
            }                                                              \
    }

    // prologue: A0(0), B0h1(0), A0h1... order fixes the vmcnt ledger:
    // loads 1-8 = full buf0(kt=0); 9-12 = A(1)h0, B(1)h1.
    {
        __bf16* A0l = &smem[0][0][0];
        __bf16* B0l = &smem[0][1][0];
        __bf16* A1l = &smem[1][0][0];
        __bf16* B1l = &smem[1][1][0];
        STAGE_HALF(Ag, A0l, 0, 0);
        STAGE_HALF(Bg, B0l, 1, 0);
        STAGE_HALF(Ag, A0l, 1, 0);
        STAGE_HALF(Bg, B0l, 0, 0);
        STAGE_HALF(Ag, A1l, 0, 1);
        STAGE_HALF(Bg, B1l, 1, 1);
    }

    for (int kt = 0; kt < NKT; ++kt) {
        const int cur = kt & 1;
        __bf16* Ac = &smem[cur][0][0];
        __bf16* Bc = &smem[cur][1][0];
        __bf16* An = &smem[cur ^ 1][0][0];
        __bf16* Bn = &smem[cur ^ 1][1][0];

        // ---- P1: quadrant (0,0) ----
        FENCE();
        if (kt == NKT - 1) asm volatile("s_waitcnt vmcnt(0)" ::: "memory");
        else               asm volatile("s_waitcnt vmcnt(4)" ::: "memory");
        __builtin_amdgcn_s_barrier();
        FENCE();
        LOAD_AF(Ac, 0);
        LOAD_BF(Bc, 0, bF0);
        if (kt + 1 < NKT) {
            STAGE_HALF(Ag, An, 1, kt + 1);
            STAGE_HALF(Bg, Bn, 0, kt + 1);
        }
        asm volatile("s_waitcnt lgkmcnt(0)" ::: "memory");
        __builtin_amdgcn_sched_barrier(0);
        __builtin_amdgcn_s_setprio(1);
        MFMA_QUAD(0, 0, bF0);
        __builtin_amdgcn_s_setprio(0);

        // ---- P2: quadrant (0,1) ----
        FENCE();
        __builtin_amdgcn_s_barrier();
        FENCE();
        LOAD_BF(Bc, 1, bF1);
        asm volatile("s_waitcnt lgkmcnt(0)" ::: "memory");
        __builtin_amdgcn_sched_barrier(0);
        __builtin_amdgcn_s_setprio(1);
        MFMA_QUAD(0, 1, bF1);
        __builtin_amdgcn_s_setprio(0);

        // ---- P3: quadrant (1,1) ----
        FENCE();
        __builtin_amdgcn_s_barrier();
        FENCE();
        LOAD_AF(Ac, 1);
        if (kt + 2 < NKT) STAGE_HALF(Ag, Ac, 0, kt + 2);
        asm volatile("s_waitcnt lgkmcnt(0)" ::: "memory");
        __builtin_amdgcn_sched_barrier(0);
        __builtin_amdgcn_s_setprio(1);
        MFMA_QUAD(1, 1, bF1);
        __builtin_amdgcn_s_setprio(0);

        // ---- P4: quadrant (1,0) ----
        FENCE();
        __builtin_amdgcn_s_barrier();
        FENCE();
        if (kt + 2 < NKT) STAGE_HALF(Bg, Bc, 1, kt + 2);
        __builtin_amdgcn_s_setprio(1);
        MFMA_QUAD(1, 0, bF0);
        __builtin_amdgcn_s_setprio(0);
    }

    // epilogue: bias + store
    const int row0 = m0 + wm * 128 + (lane >> 4) * 4;
    const int col0 = n0 + wn * 64 + fr;
#pragma unroll
    for (int f = 0; f < 8; ++f)
#pragma unroll
        for (int g = 0; g < 4; ++g)
#pragma unroll
            for (int rr = 0; rr < 4; ++rr)
                out[(size_t)(row0 + f * 16 + rr) * D_OUT + (col0 + g * 16)] =
                    acc[f][g][rr] + bias_v[g];

#undef STAGE_HALF
#undef LOAD_AF
#undef LOAD_BF
#undef MFMA_QUAD
}

// ---------------------------------------------------------------------------
extern "C" void kernel_launch(void* const* d_in, const int* in_sizes, int n_in,
                              void* d_out, int out_size, void* d_ws, size_t ws_size,
                              hipStream_t stream) {
    const float* x    = (const float*)d_in[0];
    const int*   mask = (const int*)d_in[1];
    const float* W    = (const float*)d_in[2];
    const float* bias = (const float*)d_in[3];
    float*       out  = (float*)d_out;

    __bf16* wsA   = (__bf16*)((char*)d_ws + WS_A_OFF);
    __bf16* wsW   = (__bf16*)((char*)d_ws + WS_W_OFF);
    int*    s_arr = (int*)((char*)d_ws + WS_S_OFF);

    mask_sum_kernel<<<dim3(N_BATCH), dim3(256), 0, stream>>>(mask, s_arr);

    convert_kernel<<<dim3(M_DIM + D_OUT), dim3(256), 0, stream>>>(
        x, W, s_arr, wsA, wsW);

    const int grid = (M_DIM / BM) * (D_OUT / BN);  // 64 * 4 = 256
    gemm_kernel<<<dim3(grid), dim3(512), 0, stream>>>(wsA, wsW, bias, out);
}